// Round 3
// baseline (96.984 us; speedup 1.0000x reference)
//
#include <hip/hip_runtime.h>

typedef short short8 __attribute__((ext_vector_type(8)));
typedef float f32x4 __attribute__((ext_vector_type(4)));

__device__ __forceinline__ unsigned short f2bf(float f) {
    union { float f; unsigned int i; } v; v.f = f;
    return (unsigned short)((v.i + 0x7fffu + ((v.i >> 16) & 1u)) >> 16);   // RNE
}

// ---------------- K1: streaming weighted-moment partials ----------------
// grid = nodes*4 blocks x 256 thr; one wave per 16-edge tile (8192 tiles).
// No LDS, no barriers. part[tile][132]: [0..127]=mom[c][f], [128..131]=mom0[c].
__global__ __launch_bounds__(256, 4)
void tp_moments(const float* __restrict__ edge_attr,   // [B,256,256,32]
                const float* __restrict__ edge_sh,     // [B,256,256,4]
                const float* __restrict__ mask,        // [B,256]
                const float* __restrict__ fc_w1,       // [32,32]
                const float* __restrict__ fc_b1,       // [32]
                float* __restrict__ part)              // [nodes*16][132]
{
    const int t = threadIdx.x;
    const int wv = t >> 6, ln = t & 63, q = ln >> 4, fc = ln & 15;
    const int tile = blockIdx.x * 4 + wv;      // 0..8191
    const int node = tile >> 4;                // 0..511
    const int T = tile & 15;
    const int b = node >> 8, n = node & 255;
    const int e0 = T * 16;

    // B-fragments: lane(q,fc) holds W1[k=q*8+j][f=fc(+16)]  (L1/L2-hit gather)
    short8 bf0, bf1;
    #pragma unroll
    for (int j = 0; j < 8; ++j) {
        int k = q * 8 + j;
        bf0[j] = (short)f2bf(fc_w1[k * 32 + fc]);
        bf1[j] = (short)f2bf(fc_w1[k * 32 + 16 + fc]);
    }
    float b1a = fc_b1[fc], b1b = fc_b1[16 + fc];

    // A-fragment: lane(q,fc) holds ea[row e0+fc][k=q*8+j], fp32->bf16
    const float* ar = edge_attr + (size_t)node * 8192 + (size_t)(e0 + fc) * 32 + q * 8;
    float4 a0 = *(const float4*)ar;
    float4 a1 = *(const float4*)(ar + 4);
    short8 af;
    af[0] = (short)f2bf(a0.x); af[1] = (short)f2bf(a0.y);
    af[2] = (short)f2bf(a0.z); af[3] = (short)f2bf(a0.w);
    af[4] = (short)f2bf(a1.x); af[5] = (short)f2bf(a1.y);
    af[6] = (short)f2bf(a1.z); af[7] = (short)f2bf(a1.w);

    // per-lane edge weights for C-layout edges e0 + q*4 + r
    float4 mk4 = *(const float4*)(mask + b * 256 + e0 + q * 4);
    float mkk[4] = { mk4.x, mk4.y, mk4.z, mk4.w };
    float wc[4][4];
    #pragma unroll
    for (int r = 0; r < 4; ++r) {
        int er = e0 + q * 4 + r;
        float excl = (er == n) ? 0.f : mkk[r];     // self-edge excluded
        float4 sh = *(const float4*)(edge_sh + ((size_t)node * 256 + er) * 4);
        wc[0][r] = excl * sh.x; wc[1][r] = excl * sh.y;
        wc[2][r] = excl * sh.z; wc[3][r] = excl * sh.w;
    }

    f32x4 z = { 0.f, 0.f, 0.f, 0.f };
    f32x4 acc0 = __builtin_amdgcn_mfma_f32_16x16x32_bf16(af, bf0, z, 0, 0, 0);
    f32x4 acc1 = __builtin_amdgcn_mfma_f32_16x16x32_bf16(af, bf1, z, 0, 0, 0);

    float pmc[4][2] = {{0,0},{0,0},{0,0},{0,0}};
    float pm0[4] = {0,0,0,0};
    #pragma unroll
    for (int r = 0; r < 4; ++r) {
        float h0 = acc0[r] + b1a; h0 = h0 > 0.f ? h0 : 0.f;
        float h1 = acc1[r] + b1b; h1 = h1 > 0.f ? h1 : 0.f;
        #pragma unroll
        for (int c = 0; c < 4; ++c) {
            float w = wc[c][r];
            pmc[c][0] += h0 * w;
            pmc[c][1] += h1 * w;
            pm0[c]    += w;
        }
    }

    // reduce over q (lanes differing in bits 4,5), write per-tile partial
    float* pt = part + (size_t)tile * 132;
    #pragma unroll
    for (int c = 0; c < 4; ++c) {
        #pragma unroll
        for (int ft = 0; ft < 2; ++ft) {
            float v = pmc[c][ft];
            v += __shfl_xor(v, 16);
            v += __shfl_xor(v, 32);
            if (q == 0) pt[c * 32 + ft * 16 + fc] = v;
        }
        float v0 = pm0[c];
        v0 += __shfl_xor(v0, 16);
        v0 += __shfl_xor(v0, 32);
        if (ln == 0) pt[128 + c] = v0;
    }
}

// ---------------- K2: per-node finish ----------------
__global__ __launch_bounds__(256, 2)
void tp_finish(const float* __restrict__ part,        // [nodes*16][132]
               const float* __restrict__ node_attr,   // [B,256,64]
               const float* __restrict__ mask,        // [B,256]
               const float* __restrict__ wlis, const float* __restrict__ wliv,
               const float* __restrict__ fc_w2,       // [32,1024]
               const float* __restrict__ fc_b2,       // [1024]
               const float* __restrict__ wlos, const float* __restrict__ wlov,
               float* __restrict__ out)               // [B,256,64]
{
    const int node = blockIdx.x;
    const int b = node >> 8;
    const int t = threadIdx.x;

    __shared__ float s_mom[128];
    __shared__ float s_mom0[4];
    __shared__ float s_scale;
    __shared__ float s_sin[16];
    __shared__ float s_vin[48];
    __shared__ __align__(16) float s_eff[8 * 256];
    __shared__ float s_pre[16];
    __shared__ float s_prev[48];

    // ---- step 1: moments, s_in/v_in, scale ----
    if (t < 128) {
        const float* p = part + (size_t)node * 16 * 132 + t;
        float a = 0.f;
        #pragma unroll
        for (int T = 0; T < 16; ++T) a += p[T * 132];
        s_mom[t] = a;
    } else if (t < 144) {
        int o = t - 128;
        const float* na = node_attr + (size_t)node * 64;
        float a = 0.f;
        #pragma unroll
        for (int i = 0; i < 16; ++i) a += na[i] * wlis[i * 16 + o];
        s_sin[o] = a * 0.25f;
    } else if (t < 192) {
        int idx = t - 144;
        int o = idx / 3, x = idx - o * 3;
        const float* na = node_attr + (size_t)node * 64;
        float a = 0.f;
        #pragma unroll
        for (int i = 0; i < 16; ++i) a += na[16 + i * 3 + x] * wliv[i * 16 + o];
        s_vin[idx] = a * 0.25f;
    } else {
        int lane = t - 192;     // whole wave 3 takes this branch (uniform)
        float4 mv = *(const float4*)(mask + b * 256 + lane * 4);
        float ms = mv.x + mv.y + mv.z + mv.w;
        ms += __shfl_xor(ms, 1);  ms += __shfl_xor(ms, 2);  ms += __shfl_xor(ms, 4);
        ms += __shfl_xor(ms, 8);  ms += __shfl_xor(ms, 16); ms += __shfl_xor(ms, 32);
        if (lane == 0) s_scale = 0.17677669529663687f / (ms - 1.0f);  // inv_fan/dsum
        if (lane >= 16 && lane < 20) {
            int c = lane - 16;
            const float* p = part + (size_t)node * 16 * 132 + 128 + c;
            float a = 0.f;
            #pragma unroll
            for (int T = 0; T < 16; ++T) a += p[T * 132];
            s_mom0[c] = a;
        }
    }
    __syncthreads();

    // ---- step 2: eff matrices; wave-uniform wblk, no duplicate fc_w2 loads ----
    {
        const int wblk = t >> 6;          // wave-uniform
        const int col0 = (t & 63) * 4;
        const float* w2g = fc_w2 + wblk * 256 + col0;
        float4 bb = *(const float4*)(fc_b2 + wblk * 256 + col0);
        if (wblk == 0 || wblk == 3) {
            float m0 = s_mom0[0];
            float a0 = m0 * bb.x, a1 = m0 * bb.y, a2 = m0 * bb.z, a3 = m0 * bb.w;
            #pragma unroll 4
            for (int f = 0; f < 32; ++f) {
                float4 w = *(const float4*)(w2g + f * 1024);
                float mf = s_mom[f];                       // c = 0
                a0 += mf * w.x; a1 += mf * w.y; a2 += mf * w.z; a3 += mf * w.w;
            }
            float* d = s_eff + ((wblk == 0) ? 0 : 7) * 256 + col0;
            d[0] = a0; d[1] = a1; d[2] = a2; d[3] = a3;
        } else {
            float m1 = s_mom0[1], m2 = s_mom0[2], m3 = s_mom0[3];
            float A1[4] = { m1*bb.x, m1*bb.y, m1*bb.z, m1*bb.w };
            float A2[4] = { m2*bb.x, m2*bb.y, m2*bb.z, m2*bb.w };
            float A3[4] = { m3*bb.x, m3*bb.y, m3*bb.z, m3*bb.w };
            #pragma unroll 4
            for (int f = 0; f < 32; ++f) {
                float4 w = *(const float4*)(w2g + f * 1024);
                float mf1 = s_mom[32 + f], mf2 = s_mom[64 + f], mf3 = s_mom[96 + f];
                A1[0] += mf1 * w.x; A1[1] += mf1 * w.y; A1[2] += mf1 * w.z; A1[3] += mf1 * w.w;
                A2[0] += mf2 * w.x; A2[1] += mf2 * w.y; A2[2] += mf2 * w.z; A2[3] += mf2 * w.w;
                A3[0] += mf3 * w.x; A3[1] += mf3 * w.y; A3[2] += mf3 * w.z; A3[3] += mf3 * w.w;
            }
            int e8b = (wblk == 1) ? 1 : 4;
            float* d1 = s_eff + (e8b + 0) * 256 + col0;
            float* d2 = s_eff + (e8b + 1) * 256 + col0;
            float* d3 = s_eff + (e8b + 2) * 256 + col0;
            #pragma unroll
            for (int j = 0; j < 4; ++j) { d1[j] = A1[j]; d2[j] = A2[j]; d3[j] = A3[j]; }
        }
    }
    __syncthreads();

    // ---- step 3: contract with s_in / v_in ----
    {
        const float inv_s3 = 0.5773502691896258f;
        if (t < 16) {
            int o = t;
            float a = 0.f;
            #pragma unroll
            for (int i = 0; i < 16; ++i) a += s_sin[i] * s_eff[0 * 256 + i * 16 + o];
            float bs = 0.f;
            #pragma unroll
            for (int x = 0; x < 3; ++x)
                #pragma unroll
                for (int i = 0; i < 16; ++i)
                    bs += s_vin[i * 3 + x] * s_eff[(1 + x) * 256 + i * 16 + o];
            s_pre[o] = (a + bs * inv_s3) * s_scale;
        } else if (t < 64) {
            int idx = t - 16;
            int o = idx / 3, x = idx - o * 3;
            float a = 0.f;
            #pragma unroll
            for (int i = 0; i < 16; ++i) a += s_sin[i] * s_eff[(4 + x) * 256 + i * 16 + o];
            float bs = 0.f;
            #pragma unroll
            for (int i = 0; i < 16; ++i) bs += s_vin[i * 3 + x] * s_eff[7 * 256 + i * 16 + o];
            s_prev[idx] = (a + bs) * s_scale;
        }
    }
    __syncthreads();

    // ---- step 4: output linear + residual ----
    if (t < 16) {
        int o = t;
        float a = 0.f;
        #pragma unroll
        for (int i = 0; i < 16; ++i) a += s_pre[i] * wlos[i * 16 + o];
        const float* na = node_attr + (size_t)node * 64;
        out[(size_t)node * 64 + o] = a * 0.25f + na[o];
    } else if (t < 64) {
        int idx = t - 16;
        int o = idx / 3, x = idx - o * 3;
        float a = 0.f;
        #pragma unroll
        for (int i = 0; i < 16; ++i) a += s_prev[i * 3 + x] * wlov[i * 16 + o];
        const float* na = node_attr + (size_t)node * 64;
        out[(size_t)node * 64 + 16 + idx] = a * 0.25f + na[16 + idx];
    }
}

extern "C" void kernel_launch(void* const* d_in, const int* in_sizes, int n_in,
                              void* d_out, int out_size, void* d_ws, size_t ws_size,
                              hipStream_t stream) {
    (void)n_in; (void)ws_size; (void)out_size;
    const float* node_attr = (const float*)d_in[0];
    const float* edge_attr = (const float*)d_in[1];
    const float* edge_sh   = (const float*)d_in[2];
    const float* maskp     = (const float*)d_in[3];
    const float* wlis      = (const float*)d_in[4];
    const float* wliv      = (const float*)d_in[5];
    const float* fc_w1     = (const float*)d_in[6];
    const float* fc_b1     = (const float*)d_in[7];
    const float* fc_w2     = (const float*)d_in[8];
    const float* fc_b2     = (const float*)d_in[9];
    const float* wlos      = (const float*)d_in[10];
    const float* wlov      = (const float*)d_in[11];
    float* outp = (float*)d_out;
    float* part = (float*)d_ws;    // nodes*16*132 floats = 4.3 MB

    int nodes = in_sizes[0] / 64;   // B*N = 512
    tp_moments<<<dim3(nodes * 4), dim3(256), 0, stream>>>(
        edge_attr, edge_sh, maskp, fc_w1, fc_b1, part);
    tp_finish<<<dim3(nodes), dim3(256), 0, stream>>>(
        part, node_attr, maskp, wlis, wliv, fc_w2, fc_b2, wlos, wlov, outp);
}